// Round 2
// baseline (2543.775 us; speedup 1.0000x reference)
//
#include <hip/hip_runtime.h>
#include <stdint.h>

// Problem constants
#define N_TOK 32768   // B*H*W = 32*32*32 tokens
#define DIM   256     // embedding dim
#define KCB   8192    // codebook entries
#define HWSZ  1024    // H*W

// ---- workspace layout (float offsets) ----  total 13,189,122 floats = 52.8 MB
#define WS_FLATT   0u          // flatT [DIM][N_TOK]           8,388,608
#define WS_CBT     8388608u    // cbT   [DIM][KCB]             2,097,152
#define WS_A32     10485760u   // a[n] = np-fp32 sum z^2       32,768
#define WS_B32     10518528u   // b[k] = np-fp32 sum e^2       8,192
#define WS_IDX     10526720u   // final argmin (int)           32,768
#define WS_CAND    10559488u   // candidates [N_TOK][16] int   524,288
#define WS_COUNTS  11083776u   // histogram (float)            8,192
#define WS_DW      11091968u   // segment-sum of z             2,097,152
#define WS_LOSS    13189120u   // double accumulator           2
#define WS_TOTAL   13189122u

// ---- output layout (float offsets, reference return order) ----
#define O_LOSS 0u
#define O_Q    1u          // quantized_st as [B,C,H,W], 8,388,608
#define O_IDX  8388609u    // indices [B,HW] as float,   32,768
#define O_CNT  8421377u    // new_count,                 8,192
#define O_W    8429569u    // new_weight,                2,097,152
#define O_CB   10526721u   // new_codebook,              2,097,152

// ===================== prep: transpose x -> flatT =====================
__global__ void k_tx(const float* __restrict__ x, float* __restrict__ flatT){
  int t = blockIdx.x * 256 + threadIdx.x;      // 2,097,152 threads
  int fid = t * 4;
  int b  = fid >> 18;
  int r  = fid & 262143;
  int c  = r >> 10;
  int hw = r & 1023;
  float4 v = *(const float4*)(x + fid);
  *(float4*)(flatT + (size_t)c * N_TOK + b * HWSZ + hw) = v;
}

// ===================== prep: transpose codebook -> cbT =====================
__global__ void k_tcb(const float* __restrict__ cb, float* __restrict__ cbT){
  __shared__ float tile[64][65];
  int bx = blockIdx.x;                 // 512 blocks: 128 k-tiles x 4 d-tiles
  int k0 = (bx >> 2) * 64, d0 = (bx & 3) * 64;
  int t = threadIdx.x, rr = t >> 4, cc = (t & 15) * 4;
  #pragma unroll
  for (int j = 0; j < 4; j++){
    int row = rr + j * 16;
    float4 v = *(const float4*)(cb + (size_t)(k0 + row) * DIM + d0 + cc);
    tile[row][cc] = v.x; tile[row][cc+1] = v.y; tile[row][cc+2] = v.z; tile[row][cc+3] = v.w;
  }
  __syncthreads();
  #pragma unroll
  for (int j = 0; j < 4; j++){
    int drow = rr + j * 16;
    float4 w = { tile[cc][drow], tile[cc+1][drow], tile[cc+2][drow], tile[cc+3][drow] };
    *(float4*)(cbT + (size_t)(d0 + drow) * KCB + k0 + cc) = w;
  }
}

// ===================== prep: squared norms, numpy pairwise fp32 order ==========
// emulates np.sum(v*v, axis=-1) for n=256: two 128-halves, each with numpy's
// 8-accumulator unrolled scheme; squares rounded separately (NO fma).
__device__ __forceinline__ float np_pairwise_sq(const float* __restrict__ p, int stride){
  #pragma clang fp contract(off)
  float h[2];
  #pragma unroll
  for (int half = 0; half < 2; half++){
    const float* q = p + half * 128 * stride;
    float r[8];
    #pragma unroll
    for (int j = 0; j < 8; j++){ float z = q[j * stride]; r[j] = z * z; }
    for (int i = 8; i < 128; i += 8){
      #pragma unroll
      for (int j = 0; j < 8; j++){ float z = q[(i + j) * stride]; r[j] = r[j] + z * z; }
    }
    h[half] = ((r[0] + r[1]) + (r[2] + r[3])) + ((r[4] + r[5]) + (r[6] + r[7]));
  }
  return h[0] + h[1];
}

__global__ void k_sqn(const float* __restrict__ flatT, const float* __restrict__ cbT,
                      float* __restrict__ a32, float* __restrict__ b32){
  int t = blockIdx.x * 256 + threadIdx.x;      // 40,960 threads
  if (t < N_TOK){
    a32[t] = np_pairwise_sq(flatT + t, N_TOK);
  } else {
    int k2 = t - N_TOK;
    b32[k2] = np_pairwise_sq(cbT + k2, KCB);
  }
}

// ===================== phase 1: fused distance GEMM + top-candidates =====================
#define TM 128
#define TN 128
#define KS 32

__device__ __forceinline__ void g2lds16(const float* gp, float* lp){
  __builtin_amdgcn_global_load_lds(
      (const __attribute__((address_space(1))) void*)gp,
      (__attribute__((address_space(3))) void*)lp, 16, 0, 0);
}

__launch_bounds__(256, 2)
__global__ void k_dist(const float* __restrict__ flatT, const float* __restrict__ cbT,
                       const float* __restrict__ a32, const float* __restrict__ b32,
                       int* __restrict__ cand)
{
  __shared__ __align__(16) float As[2][KS * TM];   // 2 x 16 KB
  __shared__ __align__(16) float Bs[2][KS * TN];   // 2 x 16 KB
  const int tid  = threadIdx.x;
  const int bx   = blockIdx.x;            // 512 blocks: 256 token tiles x 2 codebook halves
  const int tile = bx >> 1, half = bx & 1;
  const int m0   = tile * TM;
  const int tx = tid & 15, ty = tid >> 4;
  const int wave = tid >> 6, lane = tid & 63;
  const int klane = lane >> 5;
  const int mlane = (lane & 31) * 4;

  auto stage = [&](int t){
    const int ks = t & 7, chunk = t >> 3, bsel = t & 1;
    const int k0 = ks * KS;
    const int n0 = half * 4096 + chunk * TN;
    #pragma unroll
    for (int q = 0; q < 4; q++){
      const int seg = wave * 4 + q;                  // 0..15, each seg = 2 k-rows (1 KB)
      const int k = 2 * seg + klane;
      g2lds16(flatT + (size_t)(k0 + k) * N_TOK + m0 + mlane, &As[bsel][seg * 256]);
      g2lds16(cbT   + (size_t)(k0 + k) * KCB  + n0 + mlane, &Bs[bsel][seg * 256]);
    }
  };

  float am[8];
  #pragma unroll
  for (int ii = 0; ii < 4; ii++){
    am[ii]     = a32[m0 + ty * 4 + ii];
    am[4 + ii] = a32[m0 + 64 + ty * 4 + ii];
  }

  // per-thread lex-min top-2 of (binned fp32 distance, index)
  float d1[8], d2[8]; int i1[8], i2[8];
  #pragma unroll
  for (int ii = 0; ii < 8; ii++){ d1[ii] = 3.4e38f; d2[ii] = 3.4e38f; i1[ii] = 0x7fffffff; i2[ii] = 0x7fffffff; }

  stage(0);
  __syncthreads();

  for (int chunk = 0; chunk < 32; chunk++){
    float acc[8][8];
    #pragma unroll
    for (int ii = 0; ii < 8; ii++)
      #pragma unroll
      for (int jj = 0; jj < 8; jj++) acc[ii][jj] = 0.0f;

    for (int ks = 0; ks < 8; ks++){
      const int t = chunk * 8 + ks;
      if (t + 1 < 256) stage(t + 1);          // prefetch next slice
      const float* Ab = &As[t & 1][0];
      const float* Bb = &Bs[t & 1][0];
      #pragma unroll 4
      for (int k = 0; k < KS; k++){
        float4 a0 = *(const float4*)(Ab + k * TM + ty * 4);
        float4 a1 = *(const float4*)(Ab + k * TM + 64 + ty * 4);
        float4 b0 = *(const float4*)(Bb + k * TN + tx * 4);
        float4 b1 = *(const float4*)(Bb + k * TN + 64 + tx * 4);
        const float av[8] = {a0.x,a0.y,a0.z,a0.w, a1.x,a1.y,a1.z,a1.w};
        const float bv[8] = {b0.x,b0.y,b0.z,b0.w, b1.x,b1.y,b1.z,b1.w};
        #pragma unroll
        for (int ii = 0; ii < 8; ii++)
          #pragma unroll
          for (int jj = 0; jj < 8; jj++)
            acc[ii][jj] = fmaf(av[ii], bv[jj], acc[ii][jj]);
      }
      __syncthreads();
    }

    // binned fp32 distance d = fl32(fl32(a+b) - 2*s).  NOTE: even if the
    // compiler contracts A - 2*acc into fma(-2,acc,A), the result is bit
    // identical because 2*acc is exact -> single rounding either way.
    const int n0 = half * 4096 + chunk * TN;
    float bn[8];
    #pragma unroll
    for (int jj = 0; jj < 4; jj++){
      bn[jj]     = b32[n0 + tx * 4 + jj];
      bn[4 + jj] = b32[n0 + 64 + tx * 4 + jj];
    }
    #pragma unroll
    for (int ii = 0; ii < 8; ii++){
      #pragma unroll
      for (int jj = 0; jj < 8; jj++){
        const int n = n0 + ((jj < 4) ? (tx * 4 + jj) : (64 + tx * 4 + (jj - 4)));
        const float A = am[ii] + bn[jj];
        const float d = A - 2.0f * acc[ii][jj];
        // traversal is ascending n; strict < keeps the FIRST (lowest-index)
        // achiever of the min bin in d1 — np argmin tie semantics.
        if (d < d1[ii])      { d2[ii] = d1[ii]; i2[ii] = i1[ii]; d1[ii] = d; i1[ii] = n; }
        else if (d < d2[ii]) { d2[ii] = d; i2[ii] = n; }
      }
    }
  }

  // block reduction: 16 threads/token-row -> lex top-8 candidates per (token, half)
  __syncthreads();
  float4* red = (float4*)&As[0][0];   // 2048 float4 = 32 KB scratch (reuses both A buffers)
  #pragma unroll
  for (int ii = 0; ii < 8; ii++){
    const int row = (ii < 4) ? (ty * 4 + ii) : (64 + ty * 4 + (ii - 4));
    red[row * 16 + tx] = make_float4(d1[ii], __int_as_float(i1[ii]), d2[ii], __int_as_float(i2[ii]));
  }
  __syncthreads();
  if (tid < TM){
    float td[8]; int ti[8];
    #pragma unroll
    for (int j = 0; j < 8; j++){ td[j] = 3.4e38f; ti[j] = 0x7fffffff; }
    auto ins = [&](float d, int i){
      bool lt = (d < td[7]) || (d == td[7] && i < ti[7]);
      if (!lt) return;
      td[7] = d; ti[7] = i;
      #pragma unroll
      for (int j = 7; j > 0; j--){
        bool sw = (td[j] < td[j-1]) || (td[j] == td[j-1] && ti[j] < ti[j-1]);
        if (sw){ float tf = td[j]; td[j] = td[j-1]; td[j-1] = tf;
                 int tt = ti[j]; ti[j] = ti[j-1]; ti[j-1] = tt; }
      }
    };
    for (int s = 0; s < 16; s++){
      float4 e = red[tid * 16 + s];
      ins(e.x, __float_as_int(e.y));
      ins(e.z, __float_as_int(e.w));
    }
    const size_t base = ((size_t)(m0 + tid) * 2 + half) * 8;
    #pragma unroll
    for (int j = 0; j < 8; j++) cand[base + j] = ti[j];
  }
}

// ========== phase 2: np-fp32-semantics rescore (one wave / token) ==========
// d32 = fl32( fl32(a+b_k) - 2*s ) with s in fp64 (~exact; BLAS fp32 noise
// ~1e-9 only matters within 1e-9 of a rounding boundary).  argmin with
// lowest-index tie-break == np.argmin over the fp32 distance grid.
__global__ void k_pick(const float* __restrict__ x, const float* __restrict__ cb,
                       const float* __restrict__ a32, const float* __restrict__ b32,
                       const int* __restrict__ cand, int* __restrict__ idx)
{
  const int gt = blockIdx.x * 256 + threadIdx.x;
  const int n = gt >> 6;
  const int lane = gt & 63;
  const int b = n >> 10, hw = n & 1023;
  const int c0 = lane * 4;
  float z0 = x[(((size_t)b * DIM + c0 + 0) << 10) + hw];
  float z1 = x[(((size_t)b * DIM + c0 + 1) << 10) + hw];
  float z2 = x[(((size_t)b * DIM + c0 + 2) << 10) + hw];
  float z3 = x[(((size_t)b * DIM + c0 + 3) << 10) + hw];
  const float an = a32[n];
  float bestd = 3.4e38f; int besti = 0x7fffffff;
  for (int j = 0; j < 16; j++){
    const int ci = cand[(size_t)n * 16 + j];
    if (ci < 0 || ci >= KCB) continue;
    float4 e = *(const float4*)(cb + (size_t)ci * DIM + c0);
    double se = (double)z0*e.x + (double)z1*e.y + (double)z2*e.z + (double)z3*e.w;
    #pragma unroll
    for (int o = 32; o > 0; o >>= 1) se += __shfl_xor(se, o, 64);
    const float A = an + b32[ci];                 // fp32 add (b fully absorbed)
    const float d32 = (float)((double)A - 2.0 * se);
    if (d32 < bestd || (d32 == bestd && ci < besti)){ bestd = d32; besti = ci; }
  }
  if (lane == 0) idx[n] = besti;
}

// ===================== epilogue: counts + indices output =====================
__global__ void k_cnt(const int* __restrict__ idx, float* __restrict__ counts,
                      float* __restrict__ out_idx){
  int t = blockIdx.x * 256 + threadIdx.x;     // 32,768
  int i = idx[t];
  atomicAdd(counts + i, 1.0f);
  out_idx[t] = (float)i;
}

// ===================== epilogue: quantize, dw scatter, loss =====================
__global__ void k_quant(const float* __restrict__ x, const float* __restrict__ cb,
                        const int* __restrict__ idx, float* __restrict__ outq,
                        float* __restrict__ dw, double* __restrict__ loss)
{
  int t = blockIdx.x * 256 + threadIdx.x;     // 2,097,152
  int c = t >> 13;
  int g = t & 8191; int n = g * 4;
  int b = n >> 10, hw = n & 1023;
  size_t xo = (((size_t)b * DIM + c) << 10) + hw;
  float4 xv = *(const float4*)(x + xo);
  int i0 = idx[n], i1 = idx[n+1], i2 = idx[n+2], i3 = idx[n+3];
  float q0 = cb[(size_t)i0 * DIM + c];
  float q1 = cb[(size_t)i1 * DIM + c];
  float q2 = cb[(size_t)i2 * DIM + c];
  float q3 = cb[(size_t)i3 * DIM + c];
  float qd0 = q0 - xv.x, qd1 = q1 - xv.y, qd2 = q2 - xv.z, qd3 = q3 - xv.w;
  outq[xo + 0] = xv.x + qd0;
  outq[xo + 1] = xv.y + qd1;
  outq[xo + 2] = xv.z + qd2;
  outq[xo + 3] = xv.w + qd3;
  atomicAdd(dw + (size_t)i0 * DIM + c, xv.x);
  atomicAdd(dw + (size_t)i1 * DIM + c, xv.y);
  atomicAdd(dw + (size_t)i2 * DIM + c, xv.z);
  atomicAdd(dw + (size_t)i3 * DIM + c, xv.w);
  double p = (double)(qd0*qd0 + qd1*qd1 + qd2*qd2 + qd3*qd3);
  #pragma unroll
  for (int o = 32; o > 0; o >>= 1) p += __shfl_down(p, o, 64);
  if ((threadIdx.x & 63) == 0) atomicAdd(loss, p);
}

// ===================== epilogue: new_count + e_loss =====================
__global__ void k_count(const float* __restrict__ counts, const float* __restrict__ ema_count,
                        const double* __restrict__ loss, float* __restrict__ out)
{
  int k = blockIdx.x * 256 + threadIdx.x;     // 8,192
  float t1 = ema_count[k] * 0.95f;
  float t2 = 0.05f * counts[k];
  float s  = t1 + t2;
  float s2 = s + 1e-5f;
  const float DEN = (float)(32768.0 + 8192.0 * 1e-5);   // fl32(n + K*eps)
  float nc = (s2 / DEN) * 32768.0f;
  out[O_CNT + k] = nc;
  if (k == 0) out[O_LOSS] = 0.25f * (float)(loss[0] / 8388608.0);
}

// ===================== epilogue: new_weight + new_codebook =====================
__global__ void k_final(const float* __restrict__ ema_w, const float* __restrict__ dw,
                        const float* __restrict__ out_cnt,
                        float* __restrict__ out_w, float* __restrict__ out_cb)
{
  #pragma clang fp contract(off)
  int t = blockIdx.x * 256 + threadIdx.x;     // 2,097,152
  int k = t >> 8;
  float w = ema_w[t];
  float d = dw[t];
  float t1 = w * 0.95f;
  float t2 = 0.05f * d;
  float nw = t1 + t2;          // np op order; bit-exact for empty codes (d==0)
  out_w[t]  = nw;
  out_cb[t] = nw / out_cnt[k];
}

// ===================== launch =====================
extern "C" void kernel_launch(void* const* d_in, const int* in_sizes, int n_in,
                              void* d_out, int out_size, void* d_ws, size_t ws_size,
                              hipStream_t stream)
{
  const float* x         = (const float*)d_in[0];   // [32,256,32,32]
  const float* cb        = (const float*)d_in[1];   // [8192,256]
  const float* ema_count = (const float*)d_in[2];   // [8192]
  const float* ema_w     = (const float*)d_in[3];   // [8192,256]
  float* out = (float*)d_out;
  float* ws  = (float*)d_ws;

  float*  flatT  = ws + WS_FLATT;
  float*  cbT    = ws + WS_CBT;
  float*  a32    = ws + WS_A32;
  float*  b32    = ws + WS_B32;
  int*    idxp   = (int*)(ws + WS_IDX);
  int*    candp  = (int*)(ws + WS_CAND);
  float*  counts = ws + WS_COUNTS;
  float*  dwp    = ws + WS_DW;
  double* lossp  = (double*)(ws + WS_LOSS);

  hipMemsetAsync(ws + WS_COUNTS, 0, (size_t)(WS_TOTAL - WS_COUNTS) * sizeof(float), stream);

  k_tx   <<<8192, 256, 0, stream>>>(x, flatT);
  k_tcb  <<<512,  256, 0, stream>>>(cb, cbT);
  k_sqn  <<<160,  256, 0, stream>>>(flatT, cbT, a32, b32);
  k_dist <<<512,  256, 0, stream>>>(flatT, cbT, a32, b32, candp);
  k_pick <<<8192, 256, 0, stream>>>(x, cb, a32, b32, candp, idxp);
  k_cnt  <<<128,  256, 0, stream>>>(idxp, counts, out + O_IDX);
  k_quant<<<8192, 256, 0, stream>>>(x, cb, idxp, out + O_Q, dwp, lossp);
  k_count<<<32,   256, 0, stream>>>(counts, ema_count, lossp, out);
  k_final<<<8192, 256, 0, stream>>>(ema_w, dwp, out + O_CNT, out + O_W, out + O_CB);
}

// Round 5
// 975.964 us; speedup vs baseline: 2.6064x; 2.6064x over previous
//
#include <hip/hip_runtime.h>
#include <stdint.h>

// Problem constants
#define N_TOK 32768   // B*H*W tokens
#define DIM   256
#define KCB   8192
#define HWSZ  1024

// ---- workspace layout (float offsets) ---- total 7,946,242 floats = 31.8 MB
#define WS_FLATB   0u          // bf16 [32768][256]  (8,388,608 shorts)
#define WS_CBB     4194304u    // bf16 [8192][256]   (2,097,152 shorts)
#define WS_A32     5242880u    // np-fp32 ||z||^2    32,768
#define WS_B32     5275648u    // np-fp32 ||e||^2    8,192
#define WS_IDX     5283840u    // argmin (int)       32,768
#define WS_CAND    5316608u    // [token][16] int    524,288
#define WS_COUNTS  5840896u    // histogram          8,192
#define WS_DW      5849088u    // segment-sum        2,097,152
#define WS_LOSS    7946240u    // double accum       2
#define WS_TOTAL   7946242u

// ---- output layout (float offsets) ----
#define O_LOSS 0u
#define O_Q    1u
#define O_IDX  8388609u
#define O_CNT  8421377u
#define O_W    8429569u
#define O_CB   10526721u

typedef __attribute__((ext_vector_type(8))) short bf16x8;
typedef __attribute__((ext_vector_type(4))) float f32x4;

__device__ __forceinline__ void g2lds16(const void* gp, void* lp){
  __builtin_amdgcn_global_load_lds(
      (const __attribute__((address_space(1))) void*)gp,
      (__attribute__((address_space(3))) void*)lp, 16, 0, 0);
}

__device__ __forceinline__ unsigned short f2b(float f){   // fp32 -> bf16 RNE
  unsigned u = __float_as_uint(f);
  return (unsigned short)((u + 0x7FFFu + ((u >> 16) & 1u)) >> 16);
}

// ============ prep: x [B,C,H,W] -> flatB bf16 [token][c] (transpose) ============
__global__ void k_flatb(const float* __restrict__ x, unsigned short* __restrict__ flatB){
  __shared__ float tile[64][65];
  const int bx = blockIdx.x;                // 2048 = b(32) x ct(4) x ht(16)
  const int b = bx >> 6, ct = (bx >> 4) & 3, ht = bx & 15;
  const int c0 = ct * 64, hw0 = ht * 64;
  const int t = threadIdx.x, rr = t >> 4, cc4 = (t & 15) * 4;
  #pragma unroll
  for (int j = 0; j < 4; j++){
    const int crow = rr + j * 16;
    float4 v = *(const float4*)(x + ((size_t)(b * 256 + c0 + crow) << 10) + hw0 + cc4);
    tile[crow][cc4] = v.x; tile[crow][cc4+1] = v.y; tile[crow][cc4+2] = v.z; tile[crow][cc4+3] = v.w;
  }
  __syncthreads();
  #pragma unroll
  for (int j = 0; j < 4; j++){
    const int hwrow = rr + j * 16;
    ushort4 o = { f2b(tile[cc4][hwrow]), f2b(tile[cc4+1][hwrow]),
                  f2b(tile[cc4+2][hwrow]), f2b(tile[cc4+3][hwrow]) };
    *(ushort4*)(flatB + ((size_t)(b * 1024 + hw0 + hwrow) << 8) + c0 + cc4) = o;
  }
}

// ============ prep: codebook fp32 -> bf16 (no transpose) ============
__global__ void k_cbb(const float* __restrict__ cb, unsigned short* __restrict__ cbB){
  const int t = blockIdx.x * 256 + threadIdx.x;    // 524,288
  float4 v = *(const float4*)(cb + (size_t)t * 4);
  ushort4 o = { f2b(v.x), f2b(v.y), f2b(v.z), f2b(v.w) };
  *(ushort4*)(cbB + (size_t)t * 4) = o;
}

// ============ prep: squared norms, numpy pairwise fp32 order ============
__device__ __forceinline__ float np_pairwise_sq(const float* __restrict__ p, int stride){
  #pragma clang fp contract(off)
  float h[2];
  #pragma unroll
  for (int half = 0; half < 2; half++){
    const float* q = p + half * 128 * stride;
    float r[8];
    #pragma unroll
    for (int j = 0; j < 8; j++){ float z = q[j * stride]; r[j] = z * z; }
    for (int i = 8; i < 128; i += 8){
      #pragma unroll
      for (int j = 0; j < 8; j++){ float z = q[(i + j) * stride]; r[j] = r[j] + z * z; }
    }
    h[half] = ((r[0] + r[1]) + (r[2] + r[3])) + ((r[4] + r[5]) + (r[6] + r[7]));
  }
  return h[0] + h[1];
}

__global__ void k_sqn(const float* __restrict__ x, const float* __restrict__ cb,
                      float* __restrict__ a32, float* __restrict__ b32){
  int t = blockIdx.x * 256 + threadIdx.x;      // 40,960
  if (t < N_TOK){
    int b = t >> 10, hw = t & 1023;
    a32[t] = np_pairwise_sq(x + (size_t)b * 262144 + hw, 1024);  // flat[n][c], same order
  } else {
    int k2 = t - N_TOK;
    b32[k2] = np_pairwise_sq(cb + (size_t)k2 * 256, 1);
  }
}

// ============ phase 1: bf16-MFMA distance GEMM + top-8 candidates/half ============
// Block: 128 tokens x 4096 codes (one half). 4 waves (2x2 of 64x64 tiles).
// A k0..127 LDS-resident (swizzled), A k128..255 register-resident,
// B streamed as [128 codes][64 k] double-buffered slices via global_load_lds.
// Per-row candidate ranking key: (quant20(b - 2*s) << 12) | col   (u32 min = best)
__launch_bounds__(256, 2)
__global__ void k_dist(const unsigned short* __restrict__ flatB,
                       const unsigned short* __restrict__ cbB,
                       const float* __restrict__ b32,
                       int* __restrict__ cand)
{
  __shared__ __align__(16) unsigned short A1[128 * 128];   // 32 KB: [row][k0..127]
  __shared__ __align__(16) unsigned short Bs[2][128 * 64]; // 2 x 16 KB

  const int tid = threadIdx.x;
  const int bx = blockIdx.x;             // 512 = 256 token-tiles x 2 halves
  const int tt = bx >> 1, h = bx & 1;
  const int tok0 = tt * 128;
  const int wv = tid >> 6, lane = tid & 63;
  const int wy = wv >> 1, wx = wv & 1;
  const int l4 = lane >> 4, lm = lane & 15;

  const unsigned short* fB = flatB + (size_t)tok0 * 256;
  const unsigned short* cB = cbB + (size_t)h * 4096 * 256;

  // ---- stage A1 (k 0..127) and A2 (k 128..255, into Bs region) ----
  {
    const int r = lane >> 4, p = lane & 15;
    #pragma unroll
    for (int j = 0; j < 8; j++){
      const int row = wv * 32 + j * 4 + r;
      const int gc = p ^ (row & 15);
      g2lds16((const char*)fB + (size_t)row * 512 + (gc << 4),
              (char*)A1 + (wv * 32 + j * 4) * 256);
    }
    unsigned short* A2 = &Bs[0][0];
    #pragma unroll
    for (int j = 0; j < 8; j++){
      const int row = wv * 32 + j * 4 + r;
      const int gc = p ^ (row & 15);
      g2lds16((const char*)fB + (size_t)row * 512 + 256 + (gc << 4),
              (char*)A2 + (wv * 32 + j * 4) * 256);
    }
  }
  __syncthreads();

  // ---- A k128..255 fragments -> registers (16 x b128 = 64 VGPR) ----
  bf16x8 a2[4][4];
  {
    const unsigned short* A2 = &Bs[0][0];
    #pragma unroll
    for (int ks4 = 0; ks4 < 4; ks4++)
      #pragma unroll
      for (int ii = 0; ii < 4; ii++){
        const int m = wy * 64 + ii * 16 + lm;
        const int c = ks4 * 4 + l4;
        a2[ks4][ii] = *(const bf16x8*)((const char*)A2 + m * 256 + ((c ^ (m & 15)) << 4));
      }
  }
  __syncthreads();   // A2 regs loaded; Bs region now reusable for B slices

  auto stageB = [&](int S2){
    const int ss = S2 & 3, cc = S2 >> 2;
    char* dst = (char*)&Bs[S2 & 1][0];
    const int r8 = lane >> 3, p = lane & 7;
    #pragma unroll
    for (int j = 0; j < 4; j++){
      const int row = wv * 32 + j * 8 + r8;
      const int gc = p ^ (row & 7);
      g2lds16((const char*)cB + (size_t)(cc * 128 + row) * 512 + ss * 128 + (gc << 4),
              dst + (wv * 32 + j * 8) * 128);
    }
  };

  unsigned k1[16], k2[16];
  #pragma unroll
  for (int i = 0; i < 16; i++){ k1[i] = 0xFFFFFFFFu; k2[i] = 0xFFFFFFFFu; }

  f32x4 acc[4][4];
  float bn[4];

  stageB(0);
  __syncthreads();

  for (int c = 0; c < 32; c++){
    #pragma unroll
    for (int s = 0; s < 4; s++){
      const int S = c * 4 + s;
      if (S + 1 < 128) stageB(S + 1);
      const unsigned short* Bb = &Bs[S & 1][0];
      if (s == 0){
        #pragma unroll
        for (int jj = 0; jj < 4; jj++)
          bn[jj] = b32[h * 4096 + c * 128 + wx * 64 + jj * 16 + lm];
        #pragma unroll
        for (int ii = 0; ii < 4; ii++)
          #pragma unroll
          for (int jj = 0; jj < 4; jj++)
            acc[ii][jj] = (f32x4){0.f, 0.f, 0.f, 0.f};
      }
      #pragma unroll
      for (int ks2 = 0; ks2 < 2; ks2++){
        const int kg = s * 2 + ks2;          // 0..7 (compile-time)
        bf16x8 bf[4], af[4];
        #pragma unroll
        for (int jj = 0; jj < 4; jj++){
          const int n = wx * 64 + jj * 16 + lm;
          const int c2 = ks2 * 4 + l4;
          bf[jj] = *(const bf16x8*)((const char*)Bb + n * 128 + ((c2 ^ (n & 7)) << 4));
        }
        if (kg < 4){
          #pragma unroll
          for (int ii = 0; ii < 4; ii++){
            const int m = wy * 64 + ii * 16 + lm;
            const int ca = kg * 4 + l4;
            af[ii] = *(const bf16x8*)((const char*)A1 + m * 256 + ((ca ^ (m & 15)) << 4));
          }
        } else {
          #pragma unroll
          for (int ii = 0; ii < 4; ii++) af[ii] = a2[kg - 4][ii];
        }
        #pragma unroll
        for (int ii = 0; ii < 4; ii++)
          #pragma unroll
          for (int jj = 0; jj < 4; jj++)
            acc[ii][jj] = __builtin_amdgcn_mfma_f32_16x16x32_bf16(af[ii], bf[jj], acc[ii][jj], 0, 0, 0);
      }
      if (s == 3){
        #pragma unroll
        for (int ii = 0; ii < 4; ii++)
          #pragma unroll
          for (int jj = 0; jj < 4; jj++){
            const unsigned colb = (unsigned)(c * 128 + wx * 64 + jj * 16 + lm);
            #pragma unroll
            for (int r = 0; r < 4; r++){
              const float v = fmaf(-2.f, acc[ii][jj][r], bn[jj]);   // rank by b - 2s (a const/row)
              int qi = (int)fmaf(v, 4194304.f, 524288.f);           // (v + 0.125) * 2^22
              qi = qi < 0 ? 0 : (qi > 0xFFFFF ? 0xFFFFF : qi);
              const unsigned key = ((unsigned)qi << 12) | colb;
              const int rk = ii * 4 + r;
              const unsigned mx = key > k1[rk] ? key : k1[rk];
              k1[rk] = key < k1[rk] ? key : k1[rk];
              k2[rk] = mx < k2[rk] ? mx : k2[rk];
            }
          }
      }
      __syncthreads();
    }
  }

  // ---- merge: per row, top-8 of 64 keys (2 wx-waves x 16 lanes x 2) ----
  unsigned* red = (unsigned*)&A1[0];        // 32 KB = 8192 u32 = [128 rows][64]
  #pragma unroll
  for (int rk = 0; rk < 16; rk++){
    const int srow = wy * 64 + (rk >> 2) * 16 + l4 * 4 + (rk & 3);
    red[srow * 64 + wx * 32 + lm * 2 + 0] = k1[rk];
    red[srow * 64 + wx * 32 + lm * 2 + 1] = k2[rk];
  }
  __syncthreads();
  if (tid < 128){
    unsigned best[8];
    #pragma unroll
    for (int j = 0; j < 8; j++) best[j] = 0xFFFFFFFFu;
    for (int i = 0; i < 64; i++){
      unsigned k = red[tid * 64 + i];
      if (k < best[7]){
        best[7] = k;
        #pragma unroll
        for (int j = 7; j > 0; j--){
          if (best[j] < best[j-1]){ unsigned tmp = best[j]; best[j] = best[j-1]; best[j-1] = tmp; }
        }
      }
    }
    const size_t base = ((size_t)(tok0 + tid) * 2 + h) * 8;
    #pragma unroll
    for (int j = 0; j < 8; j++) cand[base + j] = h * 4096 + (int)(best[j] & 0xFFFu);
  }
}

// ========== phase 2: np-fp32-semantics rescore (one wave / token) ==========
__global__ void k_pick(const float* __restrict__ x, const float* __restrict__ cb,
                       const float* __restrict__ a32, const float* __restrict__ b32,
                       const int* __restrict__ cand, int* __restrict__ idx)
{
  const int gt = blockIdx.x * 256 + threadIdx.x;
  const int n = gt >> 6;
  const int lane = gt & 63;
  const int b = n >> 10, hw = n & 1023;
  const int c0 = lane * 4;
  float z0 = x[(((size_t)b * DIM + c0 + 0) << 10) + hw];
  float z1 = x[(((size_t)b * DIM + c0 + 1) << 10) + hw];
  float z2 = x[(((size_t)b * DIM + c0 + 2) << 10) + hw];
  float z3 = x[(((size_t)b * DIM + c0 + 3) << 10) + hw];
  const float an = a32[n];
  float bestd = 3.4e38f; int besti = 0x7fffffff;
  for (int j = 0; j < 16; j++){
    const int ci = cand[(size_t)n * 16 + j];
    if (ci < 0 || ci >= KCB) continue;
    float4 e = *(const float4*)(cb + (size_t)ci * DIM + c0);
    double se = (double)z0*e.x + (double)z1*e.y + (double)z2*e.z + (double)z3*e.w;
    #pragma unroll
    for (int o = 32; o > 0; o >>= 1) se += __shfl_xor(se, o, 64);
    const float A = an + b32[ci];
    const float d32 = (float)((double)A - 2.0 * se);
    if (d32 < bestd || (d32 == bestd && ci < besti)){ bestd = d32; besti = ci; }
  }
  if (lane == 0) idx[n] = besti;
}

// ===================== epilogue kernels (unchanged, passing) =====================
__global__ void k_cnt(const int* __restrict__ idx, float* __restrict__ counts,
                      float* __restrict__ out_idx){
  int t = blockIdx.x * 256 + threadIdx.x;
  int i = idx[t];
  atomicAdd(counts + i, 1.0f);
  out_idx[t] = (float)i;
}

__global__ void k_quant(const float* __restrict__ x, const float* __restrict__ cb,
                        const int* __restrict__ idx, float* __restrict__ outq,
                        float* __restrict__ dw, double* __restrict__ loss)
{
  int t = blockIdx.x * 256 + threadIdx.x;
  int c = t >> 13;
  int g = t & 8191; int n = g * 4;
  int b = n >> 10, hw = n & 1023;
  size_t xo = (((size_t)b * DIM + c) << 10) + hw;
  float4 xv = *(const float4*)(x + xo);
  int i0 = idx[n], i1 = idx[n+1], i2 = idx[n+2], i3 = idx[n+3];
  float q0 = cb[(size_t)i0 * DIM + c];
  float q1 = cb[(size_t)i1 * DIM + c];
  float q2 = cb[(size_t)i2 * DIM + c];
  float q3 = cb[(size_t)i3 * DIM + c];
  float qd0 = q0 - xv.x, qd1 = q1 - xv.y, qd2 = q2 - xv.z, qd3 = q3 - xv.w;
  outq[xo + 0] = xv.x + qd0;
  outq[xo + 1] = xv.y + qd1;
  outq[xo + 2] = xv.z + qd2;
  outq[xo + 3] = xv.w + qd3;
  atomicAdd(dw + (size_t)i0 * DIM + c, xv.x);
  atomicAdd(dw + (size_t)i1 * DIM + c, xv.y);
  atomicAdd(dw + (size_t)i2 * DIM + c, xv.z);
  atomicAdd(dw + (size_t)i3 * DIM + c, xv.w);
  double p = (double)(qd0*qd0 + qd1*qd1 + qd2*qd2 + qd3*qd3);
  #pragma unroll
  for (int o = 32; o > 0; o >>= 1) p += __shfl_down(p, o, 64);
  if ((threadIdx.x & 63) == 0) atomicAdd(loss, p);
}

__global__ void k_count(const float* __restrict__ counts, const float* __restrict__ ema_count,
                        const double* __restrict__ loss, float* __restrict__ out)
{
  int k = blockIdx.x * 256 + threadIdx.x;
  float t1 = ema_count[k] * 0.95f;
  float t2 = 0.05f * counts[k];
  float s  = t1 + t2;
  float s2 = s + 1e-5f;
  const float DEN = (float)(32768.0 + 8192.0 * 1e-5);
  float nc = (s2 / DEN) * 32768.0f;
  out[O_CNT + k] = nc;
  if (k == 0) out[O_LOSS] = 0.25f * (float)(loss[0] / 8388608.0);
}

__global__ void k_final(const float* __restrict__ ema_w, const float* __restrict__ dw,
                        const float* __restrict__ out_cnt,
                        float* __restrict__ out_w, float* __restrict__ out_cb)
{
  #pragma clang fp contract(off)
  int t = blockIdx.x * 256 + threadIdx.x;
  int k = t >> 8;
  float w = ema_w[t];
  float d = dw[t];
  float t1 = w * 0.95f;
  float t2 = 0.05f * d;
  float nw = t1 + t2;
  out_w[t]  = nw;
  out_cb[t] = nw / out_cnt[k];
}

// ===================== launch =====================
extern "C" void kernel_launch(void* const* d_in, const int* in_sizes, int n_in,
                              void* d_out, int out_size, void* d_ws, size_t ws_size,
                              hipStream_t stream)
{
  const float* x         = (const float*)d_in[0];
  const float* cb        = (const float*)d_in[1];
  const float* ema_count = (const float*)d_in[2];
  const float* ema_w     = (const float*)d_in[3];
  float* out = (float*)d_out;
  float* ws  = (float*)d_ws;

  unsigned short* flatB = (unsigned short*)(ws + WS_FLATB);
  unsigned short* cbB   = (unsigned short*)(ws + WS_CBB);
  float*  a32    = ws + WS_A32;
  float*  b32    = ws + WS_B32;
  int*    idxp   = (int*)(ws + WS_IDX);
  int*    candp  = (int*)(ws + WS_CAND);
  float*  counts = ws + WS_COUNTS;
  float*  dwp    = ws + WS_DW;
  double* lossp  = (double*)(ws + WS_LOSS);

  (void)hipMemsetAsync(ws + WS_COUNTS, 0, (size_t)(WS_TOTAL - WS_COUNTS) * sizeof(float), stream);

  k_flatb<<<2048, 256, 0, stream>>>(x, flatB);
  k_cbb  <<<2048, 256, 0, stream>>>(cb, cbB);
  k_sqn  <<<160,  256, 0, stream>>>(x, cb, a32, b32);
  k_dist <<<512,  256, 0, stream>>>(flatB, cbB, b32, candp);
  k_pick <<<8192, 256, 0, stream>>>(x, cb, a32, b32, candp, idxp);
  k_cnt  <<<128,  256, 0, stream>>>(idxp, counts, out + O_IDX);
  k_quant<<<8192, 256, 0, stream>>>(x, cb, idxp, out + O_Q, dwp, lossp);
  k_count<<<32,   256, 0, stream>>>(counts, ema_count, lossp, out);
  k_final<<<8192, 256, 0, stream>>>(ema_w, dwp, out + O_CNT, out + O_W, out + O_CB);
}

// Round 6
// 811.660 us; speedup vs baseline: 3.1340x; 1.2024x over previous
//
#include <hip/hip_runtime.h>
#include <stdint.h>

// Problem constants
#define N_TOK 32768   // B*H*W tokens
#define DIM   256
#define KCB   8192
#define HWSZ  1024

// ---- workspace layout (float offsets) ---- total 7,995,394 floats = 32.0 MB
#define WS_FLATB   0u          // bf16 flat [32768][256]  (4,194,304 floats of shorts)
#define WS_CBB     4194304u    // bf16 cb [8192][256]     (1,048,576)
#define WS_A32     5242880u    // np-fp32 ||z||^2         32,768
#define WS_B32     5275648u    // np-fp32 ||e||^2         8,192
#define WS_IDX     5283840u    // argmin (int)            32,768
#define WS_CAND    5316608u    // [token][16] int         524,288
#define WS_ICNT    5840896u    // int histogram           8,192   <- memset from here
#define WS_CUR     5849088u    // int cursors             8,192
#define WS_LOSS    5857280u    // double accum            2       <- memset through here
#define WS_OFFS    5857282u    // int exclusive offsets   8,192
#define WS_PERM    5865474u    // int token permutation   32,768
#define WS_DW      5898242u    // segment-sum fp32        2,097,152
#define WS_TOTAL   7995394u
#define WS_MEMSET_LEN 16386u   // ICNT + CUR + LOSS

// ---- output layout (float offsets) ----
#define O_LOSS 0u
#define O_Q    1u
#define O_IDX  8388609u
#define O_CNT  8421377u
#define O_W    8429569u
#define O_CB   10526721u

typedef __attribute__((ext_vector_type(8))) short bf16x8;
typedef __attribute__((ext_vector_type(4))) float f32x4;

__device__ __forceinline__ void g2lds16(const void* gp, void* lp){
  __builtin_amdgcn_global_load_lds(
      (const __attribute__((address_space(1))) void*)gp,
      (__attribute__((address_space(3))) void*)lp, 16, 0, 0);
}

__device__ __forceinline__ unsigned short f2b(float f){   // fp32 -> bf16 RNE
  unsigned u = __float_as_uint(f);
  return (unsigned short)((u + 0x7FFFu + ((u >> 16) & 1u)) >> 16);
}

// ============ prep: x [B,C,H,W] -> flatB bf16 [token][c] (transpose) ============
__global__ void k_flatb(const float* __restrict__ x, unsigned short* __restrict__ flatB){
  __shared__ float tile[64][65];
  const int bx = blockIdx.x;                // 2048 = b(32) x ct(4) x ht(16)
  const int b = bx >> 6, ct = (bx >> 4) & 3, ht = bx & 15;
  const int c0 = ct * 64, hw0 = ht * 64;
  const int t = threadIdx.x, rr = t >> 4, cc4 = (t & 15) * 4;
  #pragma unroll
  for (int j = 0; j < 4; j++){
    const int crow = rr + j * 16;
    float4 v = *(const float4*)(x + ((size_t)(b * 256 + c0 + crow) << 10) + hw0 + cc4);
    tile[crow][cc4] = v.x; tile[crow][cc4+1] = v.y; tile[crow][cc4+2] = v.z; tile[crow][cc4+3] = v.w;
  }
  __syncthreads();
  #pragma unroll
  for (int j = 0; j < 4; j++){
    const int hwrow = rr + j * 16;
    ushort4 o = { f2b(tile[cc4][hwrow]), f2b(tile[cc4+1][hwrow]),
                  f2b(tile[cc4+2][hwrow]), f2b(tile[cc4+3][hwrow]) };
    *(ushort4*)(flatB + ((size_t)(b * 1024 + hw0 + hwrow) << 8) + c0 + cc4) = o;
  }
}

// ============ prep: codebook fp32 -> bf16 (no transpose) ============
__global__ void k_cbb(const float* __restrict__ cb, unsigned short* __restrict__ cbB){
  const int t = blockIdx.x * 256 + threadIdx.x;    // 524,288
  float4 v = *(const float4*)(cb + (size_t)t * 4);
  ushort4 o = { f2b(v.x), f2b(v.y), f2b(v.z), f2b(v.w) };
  *(ushort4*)(cbB + (size_t)t * 4) = o;
}

// ============ prep: squared norms, numpy pairwise fp32 order ============
__device__ __forceinline__ float np_pairwise_sq(const float* __restrict__ p, int stride){
  #pragma clang fp contract(off)
  float h[2];
  #pragma unroll
  for (int half = 0; half < 2; half++){
    const float* q = p + half * 128 * stride;
    float r[8];
    #pragma unroll
    for (int j = 0; j < 8; j++){ float z = q[j * stride]; r[j] = z * z; }
    for (int i = 8; i < 128; i += 8){
      #pragma unroll
      for (int j = 0; j < 8; j++){ float z = q[(i + j) * stride]; r[j] = r[j] + z * z; }
    }
    h[half] = ((r[0] + r[1]) + (r[2] + r[3])) + ((r[4] + r[5]) + (r[6] + r[7]));
  }
  return h[0] + h[1];
}

__global__ void k_sqn(const float* __restrict__ x, const float* __restrict__ cb,
                      float* __restrict__ a32, float* __restrict__ b32){
  int t = blockIdx.x * 256 + threadIdx.x;      // 40,960
  if (t < N_TOK){
    int b = t >> 10, hw = t & 1023;
    a32[t] = np_pairwise_sq(x + (size_t)b * 262144 + hw, 1024);  // flat[n][c], same order
  } else {
    int k2 = t - N_TOK;
    b32[k2] = np_pairwise_sq(cb + (size_t)k2 * 256, 1);
  }
}

// ============ phase 1: bf16-MFMA distance GEMM + top-8 candidates/half ============
__launch_bounds__(256, 2)
__global__ void k_dist(const unsigned short* __restrict__ flatB,
                       const unsigned short* __restrict__ cbB,
                       const float* __restrict__ b32,
                       int* __restrict__ cand)
{
  __shared__ __align__(16) unsigned short A1[128 * 128];   // 32 KB: [row][k0..127]
  __shared__ __align__(16) unsigned short Bs[2][128 * 64]; // 2 x 16 KB

  const int tid = threadIdx.x;
  const int bx = blockIdx.x;             // 512 = 256 token-tiles x 2 halves
  const int tt = bx >> 1, h = bx & 1;
  const int tok0 = tt * 128;
  const int wv = tid >> 6, lane = tid & 63;
  const int wy = wv >> 1, wx = wv & 1;
  const int l4 = lane >> 4, lm = lane & 15;

  const unsigned short* fB = flatB + (size_t)tok0 * 256;
  const unsigned short* cB = cbB + (size_t)h * 4096 * 256;

  // ---- stage A1 (k 0..127) and A2 (k 128..255, into Bs region) ----
  {
    const int r = lane >> 4, p = lane & 15;
    #pragma unroll
    for (int j = 0; j < 8; j++){
      const int row = wv * 32 + j * 4 + r;
      const int gc = p ^ (row & 15);
      g2lds16((const char*)fB + (size_t)row * 512 + (gc << 4),
              (char*)A1 + (wv * 32 + j * 4) * 256);
    }
    unsigned short* A2 = &Bs[0][0];
    #pragma unroll
    for (int j = 0; j < 8; j++){
      const int row = wv * 32 + j * 4 + r;
      const int gc = p ^ (row & 15);
      g2lds16((const char*)fB + (size_t)row * 512 + 256 + (gc << 4),
              (char*)A2 + (wv * 32 + j * 4) * 256);
    }
  }
  __syncthreads();

  // ---- A k128..255 fragments -> registers (16 x b128 = 64 VGPR) ----
  bf16x8 a2[4][4];
  {
    const unsigned short* A2 = &Bs[0][0];
    #pragma unroll
    for (int ks4 = 0; ks4 < 4; ks4++)
      #pragma unroll
      for (int ii = 0; ii < 4; ii++){
        const int m = wy * 64 + ii * 16 + lm;
        const int c = ks4 * 4 + l4;
        a2[ks4][ii] = *(const bf16x8*)((const char*)A2 + m * 256 + ((c ^ (m & 15)) << 4));
      }
  }
  __syncthreads();   // A2 regs loaded; Bs region now reusable for B slices

  auto stageB = [&](int S2){
    const int ss = S2 & 3, cc = S2 >> 2;
    char* dst = (char*)&Bs[S2 & 1][0];
    const int r8 = lane >> 3, p = lane & 7;
    #pragma unroll
    for (int j = 0; j < 4; j++){
      const int row = wv * 32 + j * 8 + r8;
      const int gc = p ^ (row & 7);
      g2lds16((const char*)cB + (size_t)(cc * 128 + row) * 512 + ss * 128 + (gc << 4),
              dst + (wv * 32 + j * 8) * 128);
    }
  };

  unsigned k1[16], k2[16];
  #pragma unroll
  for (int i = 0; i < 16; i++){ k1[i] = 0xFFFFFFFFu; k2[i] = 0xFFFFFFFFu; }

  f32x4 acc[4][4];
  float bn[4];

  stageB(0);
  __syncthreads();

  for (int c = 0; c < 32; c++){
    #pragma unroll
    for (int s = 0; s < 4; s++){
      const int S = c * 4 + s;
      if (S + 1 < 128) stageB(S + 1);
      const unsigned short* Bb = &Bs[S & 1][0];
      if (s == 0){
        #pragma unroll
        for (int jj = 0; jj < 4; jj++)
          bn[jj] = b32[h * 4096 + c * 128 + wx * 64 + jj * 16 + lm];
        #pragma unroll
        for (int ii = 0; ii < 4; ii++)
          #pragma unroll
          for (int jj = 0; jj < 4; jj++)
            acc[ii][jj] = (f32x4){0.f, 0.f, 0.f, 0.f};
      }
      #pragma unroll
      for (int ks2 = 0; ks2 < 2; ks2++){
        const int kg = s * 2 + ks2;          // 0..7 (compile-time)
        bf16x8 bf[4], af[4];
        #pragma unroll
        for (int jj = 0; jj < 4; jj++){
          const int n = wx * 64 + jj * 16 + lm;
          const int c2 = ks2 * 4 + l4;
          bf[jj] = *(const bf16x8*)((const char*)Bb + n * 128 + ((c2 ^ (n & 7)) << 4));
        }
        if (kg < 4){
          #pragma unroll
          for (int ii = 0; ii < 4; ii++){
            const int m = wy * 64 + ii * 16 + lm;
            const int ca = kg * 4 + l4;
            af[ii] = *(const bf16x8*)((const char*)A1 + m * 256 + ((ca ^ (m & 15)) << 4));
          }
        } else {
          #pragma unroll
          for (int ii = 0; ii < 4; ii++) af[ii] = a2[kg - 4][ii];
        }
        #pragma unroll
        for (int ii = 0; ii < 4; ii++)
          #pragma unroll
          for (int jj = 0; jj < 4; jj++)
            acc[ii][jj] = __builtin_amdgcn_mfma_f32_16x16x32_bf16(af[ii], bf[jj], acc[ii][jj], 0, 0, 0);
      }
      if (s == 3){
        #pragma unroll
        for (int ii = 0; ii < 4; ii++)
          #pragma unroll
          for (int jj = 0; jj < 4; jj++){
            const unsigned colb = (unsigned)(c * 128 + wx * 64 + jj * 16 + lm);
            #pragma unroll
            for (int r = 0; r < 4; r++){
              const float v = fmaf(-2.f, acc[ii][jj][r], bn[jj]);   // rank by b - 2s (a const/row)
              int qi = (int)fmaf(v, 4194304.f, 524288.f);           // (v + 0.125) * 2^22
              qi = qi < 0 ? 0 : (qi > 0xFFFFF ? 0xFFFFF : qi);
              const unsigned key = ((unsigned)qi << 12) | colb;
              const int rk = ii * 4 + r;
              const unsigned mx = key > k1[rk] ? key : k1[rk];
              k1[rk] = key < k1[rk] ? key : k1[rk];
              k2[rk] = mx < k2[rk] ? mx : k2[rk];
            }
          }
      }
      __syncthreads();
    }
  }

  // ---- merge: per row, top-8 of 64 keys ----
  unsigned* red = (unsigned*)&A1[0];        // 32 KB = 8192 u32 = [128 rows][64]
  #pragma unroll
  for (int rk = 0; rk < 16; rk++){
    const int srow = wy * 64 + (rk >> 2) * 16 + l4 * 4 + (rk & 3);
    red[srow * 64 + wx * 32 + lm * 2 + 0] = k1[rk];
    red[srow * 64 + wx * 32 + lm * 2 + 1] = k2[rk];
  }
  __syncthreads();
  if (tid < 128){
    unsigned best[8];
    #pragma unroll
    for (int j = 0; j < 8; j++) best[j] = 0xFFFFFFFFu;
    for (int i = 0; i < 64; i++){
      unsigned k = red[tid * 64 + i];
      if (k < best[7]){
        best[7] = k;
        #pragma unroll
        for (int j = 7; j > 0; j--){
          if (best[j] < best[j-1]){ unsigned tmp = best[j]; best[j] = best[j-1]; best[j-1] = tmp; }
        }
      }
    }
    const size_t base = ((size_t)(tok0 + tid) * 2 + h) * 8;
    #pragma unroll
    for (int j = 0; j < 8; j++) cand[base + j] = h * 4096 + (int)(best[j] & 0xFFFu);
  }
}

// ========== phase 2: np-fp32-semantics rescore (one wave / token) ==========
__global__ void k_pick(const float* __restrict__ x, const float* __restrict__ cb,
                       const float* __restrict__ a32, const float* __restrict__ b32,
                       const int* __restrict__ cand, int* __restrict__ idx)
{
  const int gt = blockIdx.x * 256 + threadIdx.x;
  const int n = gt >> 6;
  const int lane = gt & 63;
  const int b = n >> 10, hw = n & 1023;
  const int c0 = lane * 4;
  float z0 = x[(((size_t)b * DIM + c0 + 0) << 10) + hw];
  float z1 = x[(((size_t)b * DIM + c0 + 1) << 10) + hw];
  float z2 = x[(((size_t)b * DIM + c0 + 2) << 10) + hw];
  float z3 = x[(((size_t)b * DIM + c0 + 3) << 10) + hw];
  const float an = a32[n];
  float bestd = 3.4e38f; int besti = 0x7fffffff;
  for (int j = 0; j < 16; j++){
    const int ci = cand[(size_t)n * 16 + j];
    if (ci < 0 || ci >= KCB) continue;
    float4 e = *(const float4*)(cb + (size_t)ci * DIM + c0);
    double se = (double)z0*e.x + (double)z1*e.y + (double)z2*e.z + (double)z3*e.w;
    #pragma unroll
    for (int o = 32; o > 0; o >>= 1) se += __shfl_xor(se, o, 64);
    const float A = an + b32[ci];
    const float d32 = (float)((double)A - 2.0 * se);
    if (d32 < bestd || (d32 == bestd && ci < besti)){ bestd = d32; besti = ci; }
  }
  if (lane == 0) idx[n] = besti;
}

// ===================== histogram (int) + indices output =====================
__global__ void k_cnt(const int* __restrict__ idx, int* __restrict__ icnt,
                      float* __restrict__ out_idx){
  int t = blockIdx.x * 256 + threadIdx.x;     // 32,768
  int i = idx[t];
  atomicAdd(icnt + i, 1);
  out_idx[t] = (float)i;
}

// ===================== exclusive scan of 8192 counts (1 block) =====================
__global__ void k_scan(const int* __restrict__ icnt, int* __restrict__ offs){
  __shared__ int sums[256];
  const int tid = threadIdx.x;
  int loc[32];
  int s = 0;
  #pragma unroll
  for (int i = 0; i < 32; i++){ loc[i] = s; s += icnt[tid * 32 + i]; }
  sums[tid] = s;
  #pragma unroll
  for (int off = 1; off < 256; off <<= 1){
    __syncthreads();
    const int add = (tid >= off) ? sums[tid - off] : 0;
    __syncthreads();
    sums[tid] += add;
  }
  __syncthreads();
  const int pre = (tid == 0) ? 0 : sums[tid - 1];
  #pragma unroll
  for (int i = 0; i < 32; i++) offs[tid * 32 + i] = pre + loc[i];
}

// ===================== bucket tokens by code =====================
__global__ void k_perm(const int* __restrict__ idx, const int* __restrict__ offs,
                       int* __restrict__ cur, int* __restrict__ perm){
  int t = blockIdx.x * 256 + threadIdx.x;     // 32,768
  int code = idx[t];
  int slot = atomicAdd(cur + code, 1);
  perm[offs[code] + slot] = t;
}

// ===================== dw segment-sum: one block per code, no atomics ==========
__global__ void k_dw(const unsigned short* __restrict__ flatB,
                     const int* __restrict__ offs, const int* __restrict__ icnt,
                     const int* __restrict__ perm, float* __restrict__ dw)
{
  const int k = blockIdx.x;                   // 8192
  const int c = threadIdx.x;                  // 256
  const int start = offs[k], cnt = icnt[k];
  float s = 0.f;
  for (int i = 0; i < cnt; i++){
    const int n = perm[start + i];
    s += __uint_as_float(((unsigned)flatB[((size_t)n << 8) + c]) << 16);
  }
  dw[((size_t)k << 8) + c] = s;               // empty code -> exact 0.0
}

// ===================== quantize + loss (no scatter atomics) =====================
__global__ void k_quant(const float* __restrict__ x, const float* __restrict__ cb,
                        const int* __restrict__ idx, float* __restrict__ outq,
                        double* __restrict__ loss)
{
  int t = blockIdx.x * 256 + threadIdx.x;     // 2,097,152
  int c = t >> 13;
  int g = t & 8191; int n = g * 4;
  int b = n >> 10, hw = n & 1023;
  size_t xo = (((size_t)b * DIM + c) << 10) + hw;
  float4 xv = *(const float4*)(x + xo);
  int i0 = idx[n], i1 = idx[n+1], i2 = idx[n+2], i3 = idx[n+3];
  float q0 = cb[(size_t)i0 * DIM + c];
  float q1 = cb[(size_t)i1 * DIM + c];
  float q2 = cb[(size_t)i2 * DIM + c];
  float q3 = cb[(size_t)i3 * DIM + c];
  float qd0 = q0 - xv.x, qd1 = q1 - xv.y, qd2 = q2 - xv.z, qd3 = q3 - xv.w;
  outq[xo + 0] = xv.x + qd0;
  outq[xo + 1] = xv.y + qd1;
  outq[xo + 2] = xv.z + qd2;
  outq[xo + 3] = xv.w + qd3;
  double p = (double)(qd0*qd0 + qd1*qd1 + qd2*qd2 + qd3*qd3);
  #pragma unroll
  for (int o = 32; o > 0; o >>= 1) p += __shfl_down(p, o, 64);
  if ((threadIdx.x & 63) == 0) atomicAdd(loss, p);
}

// ===================== new_count + e_loss =====================
__global__ void k_count(const int* __restrict__ icnt, const float* __restrict__ ema_count,
                        const double* __restrict__ loss, float* __restrict__ out)
{
  int k = blockIdx.x * 256 + threadIdx.x;     // 8,192
  float t1 = ema_count[k] * 0.95f;
  float t2 = 0.05f * (float)icnt[k];
  float s  = t1 + t2;
  float s2 = s + 1e-5f;
  const float DEN = (float)(32768.0 + 8192.0 * 1e-5);
  float nc = (s2 / DEN) * 32768.0f;
  out[O_CNT + k] = nc;
  if (k == 0) out[O_LOSS] = 0.25f * (float)(loss[0] / 8388608.0);
}

// ===================== new_weight + new_codebook =====================
__global__ void k_final(const float* __restrict__ ema_w, const float* __restrict__ dw,
                        const float* __restrict__ out_cnt,
                        float* __restrict__ out_w, float* __restrict__ out_cb)
{
  #pragma clang fp contract(off)
  int t = blockIdx.x * 256 + threadIdx.x;     // 2,097,152
  int k = t >> 8;
  float w = ema_w[t];
  float d = dw[t];
  float t1 = w * 0.95f;
  float t2 = 0.05f * d;
  float nw = t1 + t2;          // np op order; bit-exact for empty codes (d==0)
  out_w[t]  = nw;
  out_cb[t] = nw / out_cnt[k];
}

// ===================== launch =====================
extern "C" void kernel_launch(void* const* d_in, const int* in_sizes, int n_in,
                              void* d_out, int out_size, void* d_ws, size_t ws_size,
                              hipStream_t stream)
{
  const float* x         = (const float*)d_in[0];
  const float* cb        = (const float*)d_in[1];
  const float* ema_count = (const float*)d_in[2];
  const float* ema_w     = (const float*)d_in[3];
  float* out = (float*)d_out;
  float* ws  = (float*)d_ws;

  unsigned short* flatB = (unsigned short*)(ws + WS_FLATB);
  unsigned short* cbB   = (unsigned short*)(ws + WS_CBB);
  float*  a32    = ws + WS_A32;
  float*  b32    = ws + WS_B32;
  int*    idxp   = (int*)(ws + WS_IDX);
  int*    candp  = (int*)(ws + WS_CAND);
  int*    icnt   = (int*)(ws + WS_ICNT);
  int*    curp   = (int*)(ws + WS_CUR);
  double* lossp  = (double*)(ws + WS_LOSS);
  int*    offs   = (int*)(ws + WS_OFFS);
  int*    permp  = (int*)(ws + WS_PERM);
  float*  dwp    = ws + WS_DW;

  (void)hipMemsetAsync(ws + WS_ICNT, 0, (size_t)WS_MEMSET_LEN * sizeof(float), stream);

  k_flatb<<<2048, 256, 0, stream>>>(x, flatB);
  k_cbb  <<<2048, 256, 0, stream>>>(cb, cbB);
  k_sqn  <<<160,  256, 0, stream>>>(x, cb, a32, b32);
  k_dist <<<512,  256, 0, stream>>>(flatB, cbB, b32, candp);
  k_pick <<<8192, 256, 0, stream>>>(x, cb, a32, b32, candp, idxp);
  k_cnt  <<<128,  256, 0, stream>>>(idxp, icnt, out + O_IDX);
  k_scan <<<1,    256, 0, stream>>>(icnt, offs);
  k_perm <<<128,  256, 0, stream>>>(idxp, offs, curp, permp);
  k_dw   <<<8192, 256, 0, stream>>>(flatB, offs, icnt, permp, dwp);
  k_quant<<<8192, 256, 0, stream>>>(x, cb, idxp, out + O_Q, lossp);
  k_count<<<32,   256, 0, stream>>>(icnt, ema_count, lossp, out);
  k_final<<<8192, 256, 0, stream>>>(ema_w, dwp, out + O_CNT, out + O_W, out + O_CB);
}

// Round 7
// 458.305 us; speedup vs baseline: 5.5504x; 1.7710x over previous
//
#include <hip/hip_runtime.h>
#include <stdint.h>

// Problem constants
#define N_TOK 32768   // B*H*W tokens
#define DIM   256
#define KCB   8192
#define HWSZ  1024

// ---- workspace layout (float offsets) ---- total 8,011,776 floats = 32.0 MB
#define WS_FLATB   0u          // bf16 flat [32768][256]  (4,194,304)
#define WS_CBB     4194304u    // bf16 cb [8192][256]     (1,048,576)
#define WS_A32     5242880u    // np-fp32 ||z||^2         32,768
#define WS_B32     5275648u    // np-fp32 ||e||^2         8,192
#define WS_IDX     5283840u    // argmin (int)            32,768
#define WS_CAND    5316608u    // [token][16] int         524,288
#define WS_ICNT    5840896u    // int histogram           8,192   <- memset from here
#define WS_CUR     5849088u    // int cursors             8,192   <- memset through here
#define WS_OFFS    5857280u    // int exclusive offsets   8,192
#define WS_PERM    5865472u    // int token permutation   32,768
#define WS_LPART   5898240u    // per-block loss partials 8,192 doubles (16,384 floats)
#define WS_DW      5914624u    // segment-sum fp32        2,097,152
#define WS_TOTAL   8011776u
#define WS_MEMSET_LEN 16384u   // ICNT + CUR only

// ---- output layout (float offsets) ----
#define O_LOSS 0u
#define O_Q    1u
#define O_IDX  8388609u
#define O_CNT  8421377u
#define O_W    8429569u
#define O_CB   10526721u

typedef __attribute__((ext_vector_type(8))) short bf16x8;
typedef __attribute__((ext_vector_type(4))) float f32x4;

__device__ __forceinline__ void g2lds16(const void* gp, void* lp){
  __builtin_amdgcn_global_load_lds(
      (const __attribute__((address_space(1))) void*)gp,
      (__attribute__((address_space(3))) void*)lp, 16, 0, 0);
}

__device__ __forceinline__ unsigned short f2b(float f){   // fp32 -> bf16 RNE
  unsigned u = __float_as_uint(f);
  return (unsigned short)((u + 0x7FFFu + ((u >> 16) & 1u)) >> 16);
}

// ============ prep: x [B,C,H,W] -> flatB bf16 [token][c] (transpose) ============
__global__ void k_flatb(const float* __restrict__ x, unsigned short* __restrict__ flatB){
  __shared__ float tile[64][65];
  const int bx = blockIdx.x;                // 2048 = b(32) x ct(4) x ht(16)
  const int b = bx >> 6, ct = (bx >> 4) & 3, ht = bx & 15;
  const int c0 = ct * 64, hw0 = ht * 64;
  const int t = threadIdx.x, rr = t >> 4, cc4 = (t & 15) * 4;
  #pragma unroll
  for (int j = 0; j < 4; j++){
    const int crow = rr + j * 16;
    float4 v = *(const float4*)(x + ((size_t)(b * 256 + c0 + crow) << 10) + hw0 + cc4);
    tile[crow][cc4] = v.x; tile[crow][cc4+1] = v.y; tile[crow][cc4+2] = v.z; tile[crow][cc4+3] = v.w;
  }
  __syncthreads();
  #pragma unroll
  for (int j = 0; j < 4; j++){
    const int hwrow = rr + j * 16;
    ushort4 o = { f2b(tile[cc4][hwrow]), f2b(tile[cc4+1][hwrow]),
                  f2b(tile[cc4+2][hwrow]), f2b(tile[cc4+3][hwrow]) };
    *(ushort4*)(flatB + ((size_t)(b * 1024 + hw0 + hwrow) << 8) + c0 + cc4) = o;
  }
}

// ============ prep: codebook fp32 -> bf16 (no transpose) ============
__global__ void k_cbb(const float* __restrict__ cb, unsigned short* __restrict__ cbB){
  const int t = blockIdx.x * 256 + threadIdx.x;    // 524,288
  float4 v = *(const float4*)(cb + (size_t)t * 4);
  ushort4 o = { f2b(v.x), f2b(v.y), f2b(v.z), f2b(v.w) };
  *(ushort4*)(cbB + (size_t)t * 4) = o;
}

// ============ prep: squared norms, numpy pairwise fp32 order ============
__device__ __forceinline__ float np_pairwise_sq(const float* __restrict__ p, int stride){
  #pragma clang fp contract(off)
  float h[2];
  #pragma unroll
  for (int half = 0; half < 2; half++){
    const float* q = p + half * 128 * stride;
    float r[8];
    #pragma unroll
    for (int j = 0; j < 8; j++){ float z = q[j * stride]; r[j] = z * z; }
    for (int i = 8; i < 128; i += 8){
      #pragma unroll
      for (int j = 0; j < 8; j++){ float z = q[(i + j) * stride]; r[j] = r[j] + z * z; }
    }
    h[half] = ((r[0] + r[1]) + (r[2] + r[3])) + ((r[4] + r[5]) + (r[6] + r[7]));
  }
  return h[0] + h[1];
}

__global__ void k_sqn(const float* __restrict__ x, const float* __restrict__ cb,
                      float* __restrict__ a32, float* __restrict__ b32){
  int t = blockIdx.x * 256 + threadIdx.x;      // 40,960
  if (t < N_TOK){
    int b = t >> 10, hw = t & 1023;
    a32[t] = np_pairwise_sq(x + (size_t)b * 262144 + hw, 1024);  // flat[n][c], same order
  } else {
    int k2 = t - N_TOK;
    b32[k2] = np_pairwise_sq(cb + (size_t)k2 * 256, 1);
  }
}

// ============ phase 1: bf16-MFMA distance GEMM + top-8 candidates/half ============
__launch_bounds__(256, 2)
__global__ void k_dist(const unsigned short* __restrict__ flatB,
                       const unsigned short* __restrict__ cbB,
                       const float* __restrict__ b32,
                       int* __restrict__ cand)
{
  __shared__ __align__(16) unsigned short A1[128 * 128];   // 32 KB: [row][k0..127]
  __shared__ __align__(16) unsigned short Bs[2][128 * 64]; // 2 x 16 KB

  const int tid = threadIdx.x;
  const int bx = blockIdx.x;             // 512 = 256 token-tiles x 2 halves
  const int tt = bx >> 1, h = bx & 1;
  const int tok0 = tt * 128;
  const int wv = tid >> 6, lane = tid & 63;
  const int wy = wv >> 1, wx = wv & 1;
  const int l4 = lane >> 4, lm = lane & 15;

  const unsigned short* fB = flatB + (size_t)tok0 * 256;
  const unsigned short* cB = cbB + (size_t)h * 4096 * 256;

  // ---- stage A1 (k 0..127) and A2 (k 128..255, into Bs region) ----
  {
    const int r = lane >> 4, p = lane & 15;
    #pragma unroll
    for (int j = 0; j < 8; j++){
      const int row = wv * 32 + j * 4 + r;
      const int gc = p ^ (row & 15);
      g2lds16((const char*)fB + (size_t)row * 512 + (gc << 4),
              (char*)A1 + (wv * 32 + j * 4) * 256);
    }
    unsigned short* A2 = &Bs[0][0];
    #pragma unroll
    for (int j = 0; j < 8; j++){
      const int row = wv * 32 + j * 4 + r;
      const int gc = p ^ (row & 15);
      g2lds16((const char*)fB + (size_t)row * 512 + 256 + (gc << 4),
              (char*)A2 + (wv * 32 + j * 4) * 256);
    }
  }
  __syncthreads();

  // ---- A k128..255 fragments -> registers (16 x b128 = 64 VGPR) ----
  bf16x8 a2[4][4];
  {
    const unsigned short* A2 = &Bs[0][0];
    #pragma unroll
    for (int ks4 = 0; ks4 < 4; ks4++)
      #pragma unroll
      for (int ii = 0; ii < 4; ii++){
        const int m = wy * 64 + ii * 16 + lm;
        const int c = ks4 * 4 + l4;
        a2[ks4][ii] = *(const bf16x8*)((const char*)A2 + m * 256 + ((c ^ (m & 15)) << 4));
      }
  }
  __syncthreads();   // A2 regs loaded; Bs region now reusable for B slices

  auto stageB = [&](int S2){
    const int ss = S2 & 3, cc = S2 >> 2;
    char* dst = (char*)&Bs[S2 & 1][0];
    const int r8 = lane >> 3, p = lane & 7;
    #pragma unroll
    for (int j = 0; j < 4; j++){
      const int row = wv * 32 + j * 8 + r8;
      const int gc = p ^ (row & 7);
      g2lds16((const char*)cB + (size_t)(cc * 128 + row) * 512 + ss * 128 + (gc << 4),
              dst + (wv * 32 + j * 8) * 128);
    }
  };

  unsigned k1[16], k2[16];
  #pragma unroll
  for (int i = 0; i < 16; i++){ k1[i] = 0xFFFFFFFFu; k2[i] = 0xFFFFFFFFu; }

  f32x4 acc[4][4];
  float bn[4];

  stageB(0);
  __syncthreads();

  for (int c = 0; c < 32; c++){
    #pragma unroll
    for (int s = 0; s < 4; s++){
      const int S = c * 4 + s;
      if (S + 1 < 128) stageB(S + 1);
      const unsigned short* Bb = &Bs[S & 1][0];
      if (s == 0){
        #pragma unroll
        for (int jj = 0; jj < 4; jj++)
          bn[jj] = b32[h * 4096 + c * 128 + wx * 64 + jj * 16 + lm];
        #pragma unroll
        for (int ii = 0; ii < 4; ii++)
          #pragma unroll
          for (int jj = 0; jj < 4; jj++)
            acc[ii][jj] = (f32x4){0.f, 0.f, 0.f, 0.f};
      }
      #pragma unroll
      for (int ks2 = 0; ks2 < 2; ks2++){
        const int kg = s * 2 + ks2;          // 0..7 (compile-time)
        bf16x8 bf[4], af[4];
        #pragma unroll
        for (int jj = 0; jj < 4; jj++){
          const int n = wx * 64 + jj * 16 + lm;
          const int c2 = ks2 * 4 + l4;
          bf[jj] = *(const bf16x8*)((const char*)Bb + n * 128 + ((c2 ^ (n & 7)) << 4));
        }
        if (kg < 4){
          #pragma unroll
          for (int ii = 0; ii < 4; ii++){
            const int m = wy * 64 + ii * 16 + lm;
            const int ca = kg * 4 + l4;
            af[ii] = *(const bf16x8*)((const char*)A1 + m * 256 + ((ca ^ (m & 15)) << 4));
          }
        } else {
          #pragma unroll
          for (int ii = 0; ii < 4; ii++) af[ii] = a2[kg - 4][ii];
        }
        #pragma unroll
        for (int ii = 0; ii < 4; ii++)
          #pragma unroll
          for (int jj = 0; jj < 4; jj++)
            acc[ii][jj] = __builtin_amdgcn_mfma_f32_16x16x32_bf16(af[ii], bf[jj], acc[ii][jj], 0, 0, 0);
      }
      if (s == 3){
        #pragma unroll
        for (int ii = 0; ii < 4; ii++)
          #pragma unroll
          for (int jj = 0; jj < 4; jj++){
            const unsigned colb = (unsigned)(c * 128 + wx * 64 + jj * 16 + lm);
            #pragma unroll
            for (int r = 0; r < 4; r++){
              const float v = fmaf(-2.f, acc[ii][jj][r], bn[jj]);   // rank by b - 2s (a const/row)
              int qi = (int)fmaf(v, 4194304.f, 524288.f);           // (v + 0.125) * 2^22
              qi = qi < 0 ? 0 : (qi > 0xFFFFF ? 0xFFFFF : qi);
              const unsigned key = ((unsigned)qi << 12) | colb;
              const int rk = ii * 4 + r;
              const unsigned mx = key > k1[rk] ? key : k1[rk];
              k1[rk] = key < k1[rk] ? key : k1[rk];
              k2[rk] = mx < k2[rk] ? mx : k2[rk];
            }
          }
      }
      __syncthreads();
    }
  }

  // ---- merge: per row, top-8 of 64 keys ----
  unsigned* red = (unsigned*)&A1[0];        // 32 KB = 8192 u32 = [128 rows][64]
  #pragma unroll
  for (int rk = 0; rk < 16; rk++){
    const int srow = wy * 64 + (rk >> 2) * 16 + l4 * 4 + (rk & 3);
    red[srow * 64 + wx * 32 + lm * 2 + 0] = k1[rk];
    red[srow * 64 + wx * 32 + lm * 2 + 1] = k2[rk];
  }
  __syncthreads();
  if (tid < 128){
    unsigned best[8];
    #pragma unroll
    for (int j = 0; j < 8; j++) best[j] = 0xFFFFFFFFu;
    for (int i = 0; i < 64; i++){
      unsigned k = red[tid * 64 + i];
      if (k < best[7]){
        best[7] = k;
        #pragma unroll
        for (int j = 7; j > 0; j--){
          if (best[j] < best[j-1]){ unsigned tmp = best[j]; best[j] = best[j-1]; best[j-1] = tmp; }
        }
      }
    }
    const size_t base = ((size_t)(tok0 + tid) * 2 + h) * 8;
    #pragma unroll
    for (int j = 0; j < 8; j++) cand[base + j] = h * 4096 + (int)(best[j] & 0xFFFu);
  }
}

// ========== phase 2: np-fp32-semantics rescore (one wave / token) ==========
__global__ void k_pick(const float* __restrict__ x, const float* __restrict__ cb,
                       const float* __restrict__ a32, const float* __restrict__ b32,
                       const int* __restrict__ cand, int* __restrict__ idx)
{
  const int gt = blockIdx.x * 256 + threadIdx.x;
  const int n = gt >> 6;
  const int lane = gt & 63;
  const int b = n >> 10, hw = n & 1023;
  const int c0 = lane * 4;
  float z0 = x[(((size_t)b * DIM + c0 + 0) << 10) + hw];
  float z1 = x[(((size_t)b * DIM + c0 + 1) << 10) + hw];
  float z2 = x[(((size_t)b * DIM + c0 + 2) << 10) + hw];
  float z3 = x[(((size_t)b * DIM + c0 + 3) << 10) + hw];
  const float an = a32[n];
  float bestd = 3.4e38f; int besti = 0x7fffffff;
  for (int j = 0; j < 16; j++){
    const int ci = cand[(size_t)n * 16 + j];
    if (ci < 0 || ci >= KCB) continue;
    float4 e = *(const float4*)(cb + (size_t)ci * DIM + c0);
    double se = (double)z0*e.x + (double)z1*e.y + (double)z2*e.z + (double)z3*e.w;
    #pragma unroll
    for (int o = 32; o > 0; o >>= 1) se += __shfl_xor(se, o, 64);
    const float A = an + b32[ci];
    const float d32 = (float)((double)A - 2.0 * se);
    if (d32 < bestd || (d32 == bestd && ci < besti)){ bestd = d32; besti = ci; }
  }
  if (lane == 0) idx[n] = besti;
}

// ===================== histogram (int) + indices output =====================
__global__ void k_cnt(const int* __restrict__ idx, int* __restrict__ icnt,
                      float* __restrict__ out_idx){
  int t = blockIdx.x * 256 + threadIdx.x;     // 32,768
  int i = idx[t];
  atomicAdd(icnt + i, 1);
  out_idx[t] = (float)i;
}

// ===================== exclusive scan of 8192 counts (1 block) =====================
__global__ void k_scan(const int* __restrict__ icnt, int* __restrict__ offs){
  __shared__ int sums[256];
  const int tid = threadIdx.x;
  int loc[32];
  int s = 0;
  #pragma unroll
  for (int i = 0; i < 32; i++){ loc[i] = s; s += icnt[tid * 32 + i]; }
  sums[tid] = s;
  #pragma unroll
  for (int off = 1; off < 256; off <<= 1){
    __syncthreads();
    const int add = (tid >= off) ? sums[tid - off] : 0;
    __syncthreads();
    sums[tid] += add;
  }
  __syncthreads();
  const int pre = (tid == 0) ? 0 : sums[tid - 1];
  #pragma unroll
  for (int i = 0; i < 32; i++) offs[tid * 32 + i] = pre + loc[i];
}

// ===================== bucket tokens by code =====================
__global__ void k_perm(const int* __restrict__ idx, const int* __restrict__ offs,
                       int* __restrict__ cur, int* __restrict__ perm){
  int t = blockIdx.x * 256 + threadIdx.x;     // 32,768
  int code = idx[t];
  int slot = atomicAdd(cur + code, 1);
  perm[offs[code] + slot] = t;
}

// ===================== dw segment-sum: one block per code, no atomics ==========
__global__ void k_dw(const unsigned short* __restrict__ flatB,
                     const int* __restrict__ offs, const int* __restrict__ icnt,
                     const int* __restrict__ perm, float* __restrict__ dw)
{
  const int k = blockIdx.x;                   // 8192
  const int c = threadIdx.x;                  // 256
  const int start = offs[k], cnt = icnt[k];
  float s = 0.f;
  for (int i = 0; i < cnt; i++){
    const int n = perm[start + i];
    s += __uint_as_float(((unsigned)flatB[((size_t)n << 8) + c]) << 16);
  }
  dw[((size_t)k << 8) + c] = s;               // empty code -> exact 0.0
}

// ===================== quantize + loss partials (NO atomics) =====================
__global__ void k_quant(const float* __restrict__ x, const float* __restrict__ cb,
                        const int* __restrict__ idx, float* __restrict__ outq,
                        double* __restrict__ lpart)
{
  __shared__ double wred[4];
  int t = blockIdx.x * 256 + threadIdx.x;     // 2,097,152
  int c = t >> 13;
  int g = t & 8191; int n = g * 4;
  int b = n >> 10, hw = n & 1023;
  size_t xo = (((size_t)b * DIM + c) << 10) + hw;
  float4 xv = *(const float4*)(x + xo);
  int i0 = idx[n], i1 = idx[n+1], i2 = idx[n+2], i3 = idx[n+3];
  float q0 = cb[(size_t)i0 * DIM + c];
  float q1 = cb[(size_t)i1 * DIM + c];
  float q2 = cb[(size_t)i2 * DIM + c];
  float q3 = cb[(size_t)i3 * DIM + c];
  float qd0 = q0 - xv.x, qd1 = q1 - xv.y, qd2 = q2 - xv.z, qd3 = q3 - xv.w;
  float4 ov = { xv.x + qd0, xv.y + qd1, xv.z + qd2, xv.w + qd3 };
  *(float4*)(outq + xo) = ov;                 // xo is 16B-aligned (hw % 4 == 0)
  double p = (double)(qd0*qd0 + qd1*qd1 + qd2*qd2 + qd3*qd3);
  #pragma unroll
  for (int o = 32; o > 0; o >>= 1) p += __shfl_down(p, o, 64);
  if ((threadIdx.x & 63) == 0) wred[threadIdx.x >> 6] = p;
  __syncthreads();
  if (threadIdx.x == 0) lpart[blockIdx.x] = (wred[0] + wred[1]) + (wred[2] + wred[3]);
}

// ===================== new_count + e_loss (block 0 reduces loss partials) ==========
__global__ void k_count(const int* __restrict__ icnt, const float* __restrict__ ema_count,
                        const double* __restrict__ lpart, float* __restrict__ out)
{
  int k = blockIdx.x * 256 + threadIdx.x;     // 8,192
  float t1 = ema_count[k] * 0.95f;
  float t2 = 0.05f * (float)icnt[k];
  float s  = t1 + t2;
  float s2 = s + 1e-5f;
  const float DEN = (float)(32768.0 + 8192.0 * 1e-5);
  float nc = (s2 / DEN) * 32768.0f;
  out[O_CNT + k] = nc;
  if (blockIdx.x == 0){
    __shared__ double sred[256];
    const int tid = threadIdx.x;
    double ls = 0.0;
    for (int i = tid; i < 8192; i += 256) ls += lpart[i];
    sred[tid] = ls;
    __syncthreads();
    for (int off = 128; off > 0; off >>= 1){
      if (tid < off) sred[tid] += sred[tid + off];
      __syncthreads();
    }
    if (tid == 0) out[O_LOSS] = 0.25f * (float)(sred[0] / 8388608.0);
  }
}

// ===================== new_weight + new_codebook =====================
__global__ void k_final(const float* __restrict__ ema_w, const float* __restrict__ dw,
                        const float* __restrict__ out_cnt,
                        float* __restrict__ out_w, float* __restrict__ out_cb)
{
  #pragma clang fp contract(off)
  int t = blockIdx.x * 256 + threadIdx.x;     // 2,097,152
  int k = t >> 8;
  float w = ema_w[t];
  float d = dw[t];
  float t1 = w * 0.95f;
  float t2 = 0.05f * d;
  float nw = t1 + t2;          // np op order; bit-exact for empty codes (d==0)
  out_w[t]  = nw;
  out_cb[t] = nw / out_cnt[k];
}

// ===================== launch =====================
extern "C" void kernel_launch(void* const* d_in, const int* in_sizes, int n_in,
                              void* d_out, int out_size, void* d_ws, size_t ws_size,
                              hipStream_t stream)
{
  const float* x         = (const float*)d_in[0];
  const float* cb        = (const float*)d_in[1];
  const float* ema_count = (const float*)d_in[2];
  const float* ema_w     = (const float*)d_in[3];
  float* out = (float*)d_out;
  float* ws  = (float*)d_ws;

  unsigned short* flatB = (unsigned short*)(ws + WS_FLATB);
  unsigned short* cbB   = (unsigned short*)(ws + WS_CBB);
  float*  a32    = ws + WS_A32;
  float*  b32    = ws + WS_B32;
  int*    idxp   = (int*)(ws + WS_IDX);
  int*    candp  = (int*)(ws + WS_CAND);
  int*    icnt   = (int*)(ws + WS_ICNT);
  int*    curp   = (int*)(ws + WS_CUR);
  int*    offs   = (int*)(ws + WS_OFFS);
  int*    permp  = (int*)(ws + WS_PERM);
  double* lpart  = (double*)(ws + WS_LPART);
  float*  dwp    = ws + WS_DW;

  (void)hipMemsetAsync(ws + WS_ICNT, 0, (size_t)WS_MEMSET_LEN * sizeof(float), stream);

  k_flatb<<<2048, 256, 0, stream>>>(x, flatB);
  k_cbb  <<<2048, 256, 0, stream>>>(cb, cbB);
  k_sqn  <<<160,  256, 0, stream>>>(x, cb, a32, b32);
  k_dist <<<512,  256, 0, stream>>>(flatB, cbB, b32, candp);
  k_pick <<<8192, 256, 0, stream>>>(x, cb, a32, b32, candp, idxp);
  k_cnt  <<<128,  256, 0, stream>>>(idxp, icnt, out + O_IDX);
  k_scan <<<1,    256, 0, stream>>>(icnt, offs);
  k_perm <<<128,  256, 0, stream>>>(idxp, offs, curp, permp);
  k_dw   <<<8192, 256, 0, stream>>>(flatB, offs, icnt, permp, dwp);
  k_quant<<<8192, 256, 0, stream>>>(x, cb, idxp, out + O_Q, lpart);
  k_count<<<32,   256, 0, stream>>>(icnt, ema_count, lpart, out);
  k_final<<<8192, 256, 0, stream>>>(ema_w, dwp, out + O_CNT, out + O_W, out + O_CB);
}